// Round 11
// baseline (385.593 us; speedup 1.0000x reference)
//
#include <hip/hip_runtime.h>
#include <hip/hip_bf16.h>

// QuantizedLinear: T=8192 rows, N=K=4096, M=4096, RANK=64, CODESZ=8, CB=256.
// ws layout: x_bf16 [8192*4096] + W_eff bf16 [4096*4096] = 96 MiB.

typedef __attribute__((ext_vector_type(8))) short short8;
typedef __attribute__((ext_vector_type(16))) float f32x16;

#define T_ROWS 8192
#define NDIM   4096
#define MDIM   4096

// ---------------------------------------------------------------------------
// global -> LDS async copy, 16B/lane. LDS dest: wave-uniform base + lane*16.
__device__ __forceinline__ void gld_lds16(const void* g, void* lds_uniform) {
    __builtin_amdgcn_global_load_lds(
        (const __attribute__((address_space(1))) unsigned int*)(unsigned long long)(uintptr_t)g,
        (__attribute__((address_space(3))) unsigned int*)(unsigned int)(uintptr_t)lds_uniform,
        16, 0, 0);
}

__device__ __forceinline__ void bfly(float& a, float& b) {
    float s = a + b, d = a - b; a = s; b = d;
}

// ---------------------------------------------------------------------------
// 3-phase in-register FWHT-4096 (16 elems/thread, 2 syncthreads).
__device__ __forceinline__ void fwht16(float* v) {
#pragma unroll
    for (int h = 1; h <= 8; h <<= 1)
#pragma unroll
        for (int j = 0; j < 16; ++j)
            if (!(j & h)) bfly(v[j], v[j | h]);
}

// k1: x = fwht(input * SU) / 64, bf16 out.
__global__ __launch_bounds__(256) void fwht_in_kernel(
        const float* __restrict__ in, const float* __restrict__ SU,
        __hip_bfloat16* __restrict__ xout) {
    __shared__ float sh[4352];
    const int t = threadIdx.x;
    const size_t r = blockIdx.x;
    float v[16];
    {
        const float4* s4 = (const float4*)(in + (r << 12) + t * 16);
        const float4* u4 = (const float4*)(SU + t * 16);
#pragma unroll
        for (int q = 0; q < 4; ++q) {
            float4 a = s4[q], u = u4[q];
            v[4 * q + 0] = a.x * u.x; v[4 * q + 1] = a.y * u.y;
            v[4 * q + 2] = a.z * u.z; v[4 * q + 3] = a.w * u.w;
        }
    }
    fwht16(v);                                   // bits 0-3
#pragma unroll
    for (int j = 0; j < 16; ++j) sh[17 * t + j] = v[j];
    __syncthreads();
    const int baseB = (t & 15) + 272 * (t >> 4);
#pragma unroll
    for (int j = 0; j < 16; ++j) v[j] = sh[baseB + 17 * j];
    fwht16(v);                                   // bits 4-7
#pragma unroll
    for (int j = 0; j < 16; ++j) sh[baseB + 17 * j] = v[j];
    __syncthreads();
    const int baseC = t + (t >> 4);
#pragma unroll
    for (int j = 0; j < 16; ++j) v[j] = sh[baseC + 272 * j];
    fwht16(v);                                   // bits 8-11
    __hip_bfloat16* dst = xout + (r << 12);
#pragma unroll
    for (int j = 0; j < 16; ++j)
        dst[(j << 8) + t] = __float2bfloat16(v[j] * 0.015625f);
}

// k4: z = fwht(z) / 64 * SV, in place (f32).
__global__ __launch_bounds__(256) void fwht_out_kernel(
        float* __restrict__ z, const float* __restrict__ SV) {
    __shared__ float sh[4352];
    const int t = threadIdx.x;
    const size_t r = blockIdx.x;
    float* row = z + (r << 12);
    float v[16];
    {
        const float4* s4 = (const float4*)(row + t * 16);
#pragma unroll
        for (int q = 0; q < 4; ++q) {
            float4 a = s4[q];
            v[4 * q + 0] = a.x; v[4 * q + 1] = a.y;
            v[4 * q + 2] = a.z; v[4 * q + 3] = a.w;
        }
    }
    fwht16(v);
#pragma unroll
    for (int j = 0; j < 16; ++j) sh[17 * t + j] = v[j];
    __syncthreads();
    const int baseB = (t & 15) + 272 * (t >> 4);
#pragma unroll
    for (int j = 0; j < 16; ++j) v[j] = sh[baseB + 17 * j];
    fwht16(v);
#pragma unroll
    for (int j = 0; j < 16; ++j) sh[baseB + 17 * j] = v[j];
    __syncthreads();
    const int baseC = t + (t >> 4);
#pragma unroll
    for (int j = 0; j < 16; ++j) v[j] = sh[baseC + 272 * j];
    fwht16(v);
#pragma unroll
    for (int j = 0; j < 16; ++j)
        row[(j << 8) + t] = v[j] * 0.015625f * SV[(j << 8) + t];
}

// ---------------------------------------------------------------------------
// k2: W_eff = dequant + A@B, bf16. (unchanged)
__global__ __launch_bounds__(256) void dequant_kernel(
        const int* __restrict__ Qidxs, const float* __restrict__ cb,
        const float* __restrict__ Wscale, const float* __restrict__ A,
        const float* __restrict__ B, __hip_bfloat16* __restrict__ Weff) {
    __shared__ float At[64][68];
    __shared__ float Bs[64][68];
    __shared__ float cbs[2048];
    const int t = threadIdx.x;
    const int i0 = blockIdx.y * 64, j0 = blockIdx.x * 64;

    {
        const float* ga = A + (size_t)i0 * 64;
        const int r = t >> 2, kb = (t & 3) * 16;
#pragma unroll
        for (int j = 0; j < 16; ++j) At[kb + j][r] = ga[t * 16 + j];
        const int k = t >> 2, c0 = (t & 3) * 16;
        const float* gb = B + (size_t)k * NDIM + j0 + c0;
#pragma unroll
        for (int j = 0; j < 16; ++j) Bs[k][c0 + j] = gb[j];
#pragma unroll
        for (int j = 0; j < 8; ++j) cbs[t * 8 + j] = cb[t * 8 + j];
    }
    __syncthreads();

    const int ty = t >> 4, tx = t & 15;
    float acc[4][4];
#pragma unroll
    for (int a = 0; a < 4; ++a)
#pragma unroll
        for (int b = 0; b < 4; ++b) acc[a][b] = 0.f;

#pragma unroll 8
    for (int k = 0; k < 64; ++k) {
        const float4 av = *(const float4*)&At[k][ty * 4];
        const float4 bv = *(const float4*)&Bs[k][tx * 4];
        const float aa[4] = {av.x, av.y, av.z, av.w};
        const float bb[4] = {bv.x, bv.y, bv.z, bv.w};
#pragma unroll
        for (int ii = 0; ii < 4; ++ii)
#pragma unroll
            for (int jj = 0; jj < 4; ++jj) acc[ii][jj] += aa[ii] * bb[jj];
    }

    const float wsc = Wscale[0];
#pragma unroll
    for (int ii = 0; ii < 4; ++ii) {
        const int i = i0 + ty * 4 + ii;
        const int* qrow = Qidxs + (size_t)i * (NDIM / 8);
        union { __hip_bfloat16 h[4]; unsigned long long u; } pk;
#pragma unroll
        for (int jj = 0; jj < 4; ++jj) {
            const int j = j0 + tx * 4 + jj;
            const int idx = qrow[j >> 3];
            const float val = cbs[idx * 8 + (j & 7)] * wsc + acc[ii][jj];
            pk.h[jj] = __float2bfloat16(val);
        }
        *(unsigned long long*)&Weff[(size_t)i * NDIM + j0 + tx * 4] = pk.u;
    }
}

// ---------------------------------------------------------------------------
// k3: 256x256x(BK=64) bf16 NT GEMM — 32x32x16 MFMA, COUNTED vmcnt (T4).
// Consumption-order ledger (m201's trick): all of B(kt) is read to registers
// at tile start -> CUR.B region is dead -> stage B(kt+2) into CUR.B (2-ahead)
// and A(kt+1) into !CUR.A (1-ahead). Tile body:
//   entry [post-barrier]: buf[CUR] holds A(kt), B(kt) block-wide complete
//   RB: read B(kt) x8 b128 -> regs
//   lgkmcnt(0); barrier                  <- WAR gate for CUR.B overwrite
//   STA(kt+1)->!CUR.A x4; STB(kt+2)->CUR.B x4
//   RA j0; RA j1; MM j0; RA j2; MM j1; RA j3; MM j2; MM j3
//     (compiler inserts counted lgkmcnt between RA and MM)
//   lgkmcnt(0); vmcnt(4); barrier        <- NEWEST 4 (STB kt+2) stay in
//     flight; own-wave wait + barrier => A(kt+1),B(kt+1) block-wide. NEVER
//     vmcnt(0) in steady state (T4/m218: drain-0 vs counted = -38..-73%).
// Max outstanding = 12. Tail: kt=62 vmcnt(0) (no STB), kt=63 compute-only.
// Swizzle (round-10, measured 0 conflicts): store chunk ^= (row&7)^((row>>4)&3)
// via pre-swizzled global source; reads XOR le7^((lane>>4)&1), odd 32-row
// blocks additionally ^16 elems.
__global__ __launch_bounds__(512, 2) void gemm256_kernel(
        const __hip_bfloat16* __restrict__ X, const __hip_bfloat16* __restrict__ W,
        float* __restrict__ Z) {
    __shared__ short smem[65536];   // 128 KiB: [buf2][A 16K | B 16K elems]

    const int b = blockIdx.x;                 // 512 blocks, 512 % 8 == 0
    const int swz = (b & 7) * 64 + (b >> 3);  // XCD-bijective
    const int bm = swz >> 4, bn = swz & 15;   // 32 x 16 tiles

    const int tid = threadIdx.x;
    const int lane = tid & 63, wid = tid >> 6;
    const int wm = wid >> 2, wn = wid & 3;
    const int l31 = lane & 31, kg = lane >> 5, le7 = lane & 7;
    const int rowV = l31 * 64;                           // row offset (elems)
    const int xr = le7 ^ ((lane >> 4) & 1);              // read-side XOR
    const int ck0 = ((0 + kg) ^ xr) << 3;                // k-step chunks
    const int ck1 = ((2 + kg) ^ xr) << 3;
    const int ck2 = ((4 + kg) ^ xr) << 3;
    const int ck3 = ((6 + kg) ^ xr) << 3;
    const int wbase = wid << 9;

    const int grow = tid >> 3;
    const int scol = (((tid & 7) ^ (grow & 7) ^ ((grow >> 4) & 3)) << 3);
    const __hip_bfloat16* gA = X + (size_t)(bm * 256 + grow) * NDIM + scol;
    const __hip_bfloat16* gB = W + (size_t)(bn * 256 + grow) * NDIM + scol;

#define STA2(OFS, H, Q, BUF) gld_lds16(gA + (size_t)(((H) * 128 + (Q) * 64) * NDIM) + (OFS), \
        &smem[(BUF) * 32768 + (H) * 8192 + (Q) * 4096 + wbase])
#define STB2(OFS, H, Q, BUF) gld_lds16(gB + (size_t)(((H) * 128 + (Q) * 64) * NDIM) + (OFS), \
        &smem[(BUF) * 32768 + 16384 + (H) * 8192 + (Q) * 4096 + wbase])
#define STAGE_A(OFS, BUF) do { STA2(OFS,0,0,BUF); STA2(OFS,0,1,BUF); \
                               STA2(OFS,1,0,BUF); STA2(OFS,1,1,BUF); } while (0)
#define STAGE_B(OFS, BUF) do { STB2(OFS,0,0,BUF); STB2(OFS,0,1,BUF); \
                               STB2(OFS,1,0,BUF); STB2(OFS,1,1,BUF); } while (0)

// read A fragments for one k-step (4 x b128; odd 32-row blocks: chunk^16)
#define RA(CK, A0,A1,A2,A3) do { \
    A0 = *(const short8*)(aP + (CK)); \
    A1 = *(const short8*)(aP + 2048 + ((CK) ^ 16)); \
    A2 = *(const short8*)(aP + 4096 + (CK)); \
    A3 = *(const short8*)(aP + 6144 + ((CK) ^ 16)); \
} while (0)

#define MM32(A0,A1,A2,A3,B0,B1) do { \
    c00 = __builtin_amdgcn_mfma_f32_32x32x16_bf16(A0, B0, c00, 0, 0, 0); \
    c10 = __builtin_amdgcn_mfma_f32_32x32x16_bf16(A1, B0, c10, 0, 0, 0); \
    c01 = __builtin_amdgcn_mfma_f32_32x32x16_bf16(A0, B1, c01, 0, 0, 0); \
    c11 = __builtin_amdgcn_mfma_f32_32x32x16_bf16(A1, B1, c11, 0, 0, 0); \
    c20 = __builtin_amdgcn_mfma_f32_32x32x16_bf16(A2, B0, c20, 0, 0, 0); \
    c30 = __builtin_amdgcn_mfma_f32_32x32x16_bf16(A3, B0, c30, 0, 0, 0); \
    c21 = __builtin_amdgcn_mfma_f32_32x32x16_bf16(A2, B1, c21, 0, 0, 0); \
    c31 = __builtin_amdgcn_mfma_f32_32x32x16_bf16(A3, B1, c31, 0, 0, 0); \
} while (0)

#define TILE(CUR, DO_STA, DO_STB, VMEND, LAST) do { \
    const short* aP = smem + (CUR) * 32768 + wm * 8192 + rowV; \
    const short* bP = smem + (CUR) * 32768 + 16384 + wn * 4096 + rowV; \
    short8 b00, b01, b10, b11, b20, b21, b30, b31; \
    short8 sa0, sa1, sa2, sa3, ta0, ta1, ta2, ta3; \
    b00 = *(const short8*)(bP + ck0); \
    b01 = *(const short8*)(bP + 2048 + (ck0 ^ 16)); \
    b10 = *(const short8*)(bP + ck1); \
    b11 = *(const short8*)(bP + 2048 + (ck1 ^ 16)); \
    b20 = *(const short8*)(bP + ck2); \
    b21 = *(const short8*)(bP + 2048 + (ck2 ^ 16)); \
    b30 = *(const short8*)(bP + ck3); \
    b31 = *(const short8*)(bP + 2048 + (ck3 ^ 16)); \
    asm volatile("s_waitcnt lgkmcnt(0)" ::: "memory"); \
    __builtin_amdgcn_s_barrier();                    /* WAR gate */ \
    asm volatile("" ::: "memory"); \
    if (DO_STA) STAGE_A(64, 1 - (CUR)); \
    if (DO_STB) STAGE_B(128, (CUR)); \
    RA(ck0, sa0, sa1, sa2, sa3); \
    RA(ck1, ta0, ta1, ta2, ta3); \
    MM32(sa0, sa1, sa2, sa3, b00, b01);              /* j0 */ \
    RA(ck2, sa0, sa1, sa2, sa3); \
    MM32(ta0, ta1, ta2, ta3, b10, b11);              /* j1 */ \
    RA(ck3, ta0, ta1, ta2, ta3); \
    MM32(sa0, sa1, sa2, sa3, b20, b21);              /* j2 */ \
    MM32(ta0, ta1, ta2, ta3, b30, b31);              /* j3 */ \
    if (!(LAST)) { \
        asm volatile("s_waitcnt lgkmcnt(0)" ::: "memory"); \
        asm volatile("s_waitcnt vmcnt(" #VMEND ")" ::: "memory"); \
        __builtin_amdgcn_s_barrier(); \
        asm volatile("" ::: "memory"); \
    } \
    gA += 64; gB += 64; \
} while (0)

    f32x16 c00 = {0}, c01 = {0}, c10 = {0}, c11 = {0};
    f32x16 c20 = {0}, c21 = {0}, c30 = {0}, c31 = {0};

    // prologue: A(0),B(0) -> buf0; B(1) -> buf1.B; publish all
    STAGE_A(0, 0);
    STAGE_B(0, 0);
    STAGE_B(64, 1);
    asm volatile("s_waitcnt vmcnt(0)" ::: "memory");
    __builtin_amdgcn_s_barrier();
    asm volatile("" ::: "memory");

    for (int i = 0; i < 31; ++i) {      // kt = 0..61
        TILE(0, 1, 1, 4, 0);
        TILE(1, 1, 1, 4, 0);
    }
    TILE(0, 1, 0, 0, 0);                // kt = 62: no STB, full drain
    TILE(1, 0, 0, 0, 1);                // kt = 63: compute only

    // epilogue: 32x32 C/D layout: col = lane&31, row = (reg&3)+8*(reg>>2)+4*(lane>>5)
    const size_t r0 = (size_t)bm * 256 + wm * 128 + 4 * (lane >> 5);
    const size_t cb0 = (size_t)bn * 256 + wn * 64 + l31;
#define CWR(CC, M, N) do { \
    _Pragma("unroll") \
    for (int rg = 0; rg < 16; ++rg) \
        Z[(r0 + (M) * 32 + (rg & 3) + 8 * (rg >> 2)) * MDIM + cb0 + (N) * 32] = CC[rg]; \
} while (0)
    CWR(c00, 0, 0); CWR(c01, 0, 1);
    CWR(c10, 1, 0); CWR(c11, 1, 1);
    CWR(c20, 2, 0); CWR(c21, 2, 1);
    CWR(c30, 3, 0); CWR(c31, 3, 1);
}

// ---------------------------------------------------------------------------
extern "C" void kernel_launch(void* const* d_in, const int* in_sizes, int n_in,
                              void* d_out, int out_size, void* d_ws, size_t ws_size,
                              hipStream_t stream) {
    const float* input  = (const float*)d_in[0];
    const int*   Qidxs  = (const int*)d_in[1];
    const float* cbvals = (const float*)d_in[2];
    const float* SU     = (const float*)d_in[3];
    const float* SV     = (const float*)d_in[4];
    const float* Wscale = (const float*)d_in[5];
    const float* A      = (const float*)d_in[6];
    const float* B      = (const float*)d_in[7];
    float* out = (float*)d_out;

    __hip_bfloat16* xbf = (__hip_bfloat16*)d_ws;
    __hip_bfloat16* wbf = (__hip_bfloat16*)((char*)d_ws + (size_t)T_ROWS * NDIM * 2);

    fwht_in_kernel<<<T_ROWS, 256, 0, stream>>>(input, SU, xbf);
    dequant_kernel<<<dim3(MDIM / 64, MDIM / 64), 256, 0, stream>>>(
        Qidxs, cbvals, Wscale, A, B, wbf);
    gemm256_kernel<<<(T_ROWS / 256) * (MDIM / 256), 512, 0, stream>>>(xbf, wbf, out);
    fwht_out_kernel<<<T_ROWS, 256, 0, stream>>>(out, SV);
}

// Round 12
// 359.797 us; speedup vs baseline: 1.0717x; 1.0717x over previous
//
#include <hip/hip_runtime.h>
#include <hip/hip_bf16.h>

// QuantizedLinear: T=8192 rows, N=K=4096, M=4096, RANK=64, CODESZ=8, CB=256.
// ws layout: x_bf16 [8192*4096] + W_eff bf16 [4096*4096] = 96 MiB.

typedef __attribute__((ext_vector_type(8))) short short8;
typedef __attribute__((ext_vector_type(4))) float f32x4;

#define T_ROWS 8192
#define NDIM   4096
#define MDIM   4096

// ---------------------------------------------------------------------------
// global -> LDS async copy, 16B/lane. LDS dest: wave-uniform base + lane*16.
__device__ __forceinline__ void gld_lds16(const void* g, void* lds_uniform) {
    __builtin_amdgcn_global_load_lds(
        (const __attribute__((address_space(1))) unsigned int*)(unsigned long long)(uintptr_t)g,
        (__attribute__((address_space(3))) unsigned int*)(unsigned int)(uintptr_t)lds_uniform,
        16, 0, 0);
}

__device__ __forceinline__ void bfly(float& a, float& b) {
    float s = a + b, d = a - b; a = s; b = d;
}

// ---------------------------------------------------------------------------
// 3-phase in-register FWHT-4096 (16 elems/thread, 2 syncthreads).
__device__ __forceinline__ void fwht16(float* v) {
#pragma unroll
    for (int h = 1; h <= 8; h <<= 1)
#pragma unroll
        for (int j = 0; j < 16; ++j)
            if (!(j & h)) bfly(v[j], v[j | h]);
}

// k1: x = fwht(input * SU) / 64, bf16 out.
__global__ __launch_bounds__(256) void fwht_in_kernel(
        const float* __restrict__ in, const float* __restrict__ SU,
        __hip_bfloat16* __restrict__ xout) {
    __shared__ float sh[4352];
    const int t = threadIdx.x;
    const size_t r = blockIdx.x;
    float v[16];
    {
        const float4* s4 = (const float4*)(in + (r << 12) + t * 16);
        const float4* u4 = (const float4*)(SU + t * 16);
#pragma unroll
        for (int q = 0; q < 4; ++q) {
            float4 a = s4[q], u = u4[q];
            v[4 * q + 0] = a.x * u.x; v[4 * q + 1] = a.y * u.y;
            v[4 * q + 2] = a.z * u.z; v[4 * q + 3] = a.w * u.w;
        }
    }
    fwht16(v);                                   // bits 0-3
#pragma unroll
    for (int j = 0; j < 16; ++j) sh[17 * t + j] = v[j];
    __syncthreads();
    const int baseB = (t & 15) + 272 * (t >> 4);
#pragma unroll
    for (int j = 0; j < 16; ++j) v[j] = sh[baseB + 17 * j];
    fwht16(v);                                   // bits 4-7
#pragma unroll
    for (int j = 0; j < 16; ++j) sh[baseB + 17 * j] = v[j];
    __syncthreads();
    const int baseC = t + (t >> 4);
#pragma unroll
    for (int j = 0; j < 16; ++j) v[j] = sh[baseC + 272 * j];
    fwht16(v);                                   // bits 8-11
    __hip_bfloat16* dst = xout + (r << 12);
#pragma unroll
    for (int j = 0; j < 16; ++j)
        dst[(j << 8) + t] = __float2bfloat16(v[j] * 0.015625f);
}

// k4: z = fwht(z) / 64 * SV, in place (f32).
__global__ __launch_bounds__(256) void fwht_out_kernel(
        float* __restrict__ z, const float* __restrict__ SV) {
    __shared__ float sh[4352];
    const int t = threadIdx.x;
    const size_t r = blockIdx.x;
    float* row = z + (r << 12);
    float v[16];
    {
        const float4* s4 = (const float4*)(row + t * 16);
#pragma unroll
        for (int q = 0; q < 4; ++q) {
            float4 a = s4[q];
            v[4 * q + 0] = a.x; v[4 * q + 1] = a.y;
            v[4 * q + 2] = a.z; v[4 * q + 3] = a.w;
        }
    }
    fwht16(v);
#pragma unroll
    for (int j = 0; j < 16; ++j) sh[17 * t + j] = v[j];
    __syncthreads();
    const int baseB = (t & 15) + 272 * (t >> 4);
#pragma unroll
    for (int j = 0; j < 16; ++j) v[j] = sh[baseB + 17 * j];
    fwht16(v);
#pragma unroll
    for (int j = 0; j < 16; ++j) sh[baseB + 17 * j] = v[j];
    __syncthreads();
    const int baseC = t + (t >> 4);
#pragma unroll
    for (int j = 0; j < 16; ++j) v[j] = sh[baseC + 272 * j];
    fwht16(v);
#pragma unroll
    for (int j = 0; j < 16; ++j)
        row[(j << 8) + t] = v[j] * 0.015625f * SV[(j << 8) + t];
}

// ---------------------------------------------------------------------------
// k2: W_eff = dequant + A@B, bf16. (unchanged)
__global__ __launch_bounds__(256) void dequant_kernel(
        const int* __restrict__ Qidxs, const float* __restrict__ cb,
        const float* __restrict__ Wscale, const float* __restrict__ A,
        const float* __restrict__ B, __hip_bfloat16* __restrict__ Weff) {
    __shared__ float At[64][68];
    __shared__ float Bs[64][68];
    __shared__ float cbs[2048];
    const int t = threadIdx.x;
    const int i0 = blockIdx.y * 64, j0 = blockIdx.x * 64;

    {
        const float* ga = A + (size_t)i0 * 64;
        const int r = t >> 2, kb = (t & 3) * 16;
#pragma unroll
        for (int j = 0; j < 16; ++j) At[kb + j][r] = ga[t * 16 + j];
        const int k = t >> 2, c0 = (t & 3) * 16;
        const float* gb = B + (size_t)k * NDIM + j0 + c0;
#pragma unroll
        for (int j = 0; j < 16; ++j) Bs[k][c0 + j] = gb[j];
#pragma unroll
        for (int j = 0; j < 8; ++j) cbs[t * 8 + j] = cb[t * 8 + j];
    }
    __syncthreads();

    const int ty = t >> 4, tx = t & 15;
    float acc[4][4];
#pragma unroll
    for (int a = 0; a < 4; ++a)
#pragma unroll
        for (int b = 0; b < 4; ++b) acc[a][b] = 0.f;

#pragma unroll 8
    for (int k = 0; k < 64; ++k) {
        const float4 av = *(const float4*)&At[k][ty * 4];
        const float4 bv = *(const float4*)&Bs[k][tx * 4];
        const float aa[4] = {av.x, av.y, av.z, av.w};
        const float bb[4] = {bv.x, bv.y, bv.z, bv.w};
#pragma unroll
        for (int ii = 0; ii < 4; ++ii)
#pragma unroll
            for (int jj = 0; jj < 4; ++jj) acc[ii][jj] += aa[ii] * bb[jj];
    }

    const float wsc = Wscale[0];
#pragma unroll
    for (int ii = 0; ii < 4; ++ii) {
        const int i = i0 + ty * 4 + ii;
        const int* qrow = Qidxs + (size_t)i * (NDIM / 8);
        union { __hip_bfloat16 h[4]; unsigned long long u; } pk;
#pragma unroll
        for (int jj = 0; jj < 4; ++jj) {
            const int j = j0 + tx * 4 + jj;
            const int idx = qrow[j >> 3];
            const float val = cbs[idx * 8 + (j & 7)] * wsc + acc[ii][jj];
            pk.h[jj] = __float2bfloat16(val);
        }
        *(unsigned long long*)&Weff[(size_t)i * NDIM + j0 + tx * 4] = pk.u;
    }
}

// ---------------------------------------------------------------------------
// k3: 256x256x(BK=64) bf16 NT GEMM — ROTATED single-barrier schedule
// (round-6 structure, best measured: 236 us, 0 bank conflicts) + setprio on
// MFMA clusters (T5: pays only with role diversity — the rotation provides
// it: the trailing m6 cluster of kt-1 runs while the block's read burst and
// staging for kt flow).
//   [entry, post-barrier of kt-1]: regs hold Bf(kt) [RDB'd mid kt-1],
//       A.m0(kt) [PFA'd post-barrier], ya=A.m6(kt-1)
//   MFMA m6(kt-1) | STA(kt+1)->!CUR ; STB(kt+2)->CUR
//   RDA m2; MFMA m0 | RDA m4; MFMA m2 | RDB Bf(kt+1)<-!CUR.B ; RDA m6; MFMA m4
//   lgkmcnt(4); vmcnt(0); s_barrier ; PFA: RDA m0(kt+1) <- !CUR.A
__global__ __launch_bounds__(512, 2) void gemm256_kernel(
        const __hip_bfloat16* __restrict__ X, const __hip_bfloat16* __restrict__ W,
        float* __restrict__ Z) {
    __shared__ short smem[65536];   // 128 KiB: [buf2][A 16K | B 16K elems]

    const int b = blockIdx.x;                 // 512 blocks, 512 % 8 == 0
    const int swz = (b & 7) * 64 + (b >> 3);  // XCD-bijective
    const int bm = swz >> 4, bn = swz & 15;   // 32 x 16 tiles

    const int tid = threadIdx.x;
    const int lane = tid & 63, wid = tid >> 6;
    const int wm = wid >> 2, wn = wid & 3;
    const int lr = lane & 15, lk = lane >> 4;
    const int swb = (lr & 7) << 4;                       // read-side XOR (bytes)
    const int c0 = (((lk << 4)) ^ swb) >> 1;             // kk=0 col (elements)
    const int c1 = ((64 | (lk << 4)) ^ swb) >> 1;        // kk=1 col (elements)
    const int wbase = wid << 9;

    const int grow = tid >> 3;
    const int scol = (((tid & 7) ^ (grow & 7)) << 3);    // pre-swizzled source col
    const __hip_bfloat16* gA = X + (size_t)(bm * 256 + grow) * NDIM + scol;
    const __hip_bfloat16* gB = W + (size_t)(bn * 256 + grow) * NDIM + scol;

#define STA2(OFS, H, Q, BUF) gld_lds16(gA + (size_t)(((H) * 128 + (Q) * 64) * NDIM) + (OFS), \
        &smem[(BUF) * 32768 + (H) * 8192 + (Q) * 4096 + wbase])
#define STB2(OFS, H, Q, BUF) gld_lds16(gB + (size_t)(((H) * 128 + (Q) * 64) * NDIM) + (OFS), \
        &smem[(BUF) * 32768 + 16384 + (H) * 8192 + (Q) * 4096 + wbase])
#define STAGE_A(OFS, BUF) do { STA2(OFS,0,0,BUF); STA2(OFS,0,1,BUF); \
                               STA2(OFS,1,0,BUF); STA2(OFS,1,1,BUF); } while (0)
#define STAGE_B(OFS, BUF) do { STB2(OFS,0,0,BUF); STB2(OFS,0,1,BUF); \
                               STB2(OFS,1,0,BUF); STB2(OFS,1,1,BUF); } while (0)

#define RDA(D0, D1, D2, D3, M0, AB) do { \
    D0 = *(const short8*)((AB) + ((M0) * 16 + lr) * 64 + c0); \
    D1 = *(const short8*)((AB) + ((M0) * 16 + lr) * 64 + c1); \
    D2 = *(const short8*)((AB) + ((M0) * 16 + 16 + lr) * 64 + c0); \
    D3 = *(const short8*)((AB) + ((M0) * 16 + 16 + lr) * 64 + c1); \
} while (0)

#define RDB(BARR, BUF) do { \
    const short* bB_ = smem + (BUF) * 32768 + 16384 + (wn * 64 + lr) * 64; \
    _Pragma("unroll") \
    for (int n = 0; n < 4; ++n) { \
        BARR[2 * n]     = *(const short8*)(bB_ + n * 1024 + c0); \
        BARR[2 * n + 1] = *(const short8*)(bB_ + n * 1024 + c1); \
    } \
} while (0)

#define MFMA2(A0, A1, E0, E1, M0, BF) do { \
    __builtin_amdgcn_s_setprio(1); \
    _Pragma("unroll") \
    for (int n = 0; n < 4; ++n) \
        acc[M0][n] = __builtin_amdgcn_mfma_f32_16x16x32_bf16(A0, BF[2 * n], acc[M0][n], 0, 0, 0); \
    _Pragma("unroll") \
    for (int n = 0; n < 4; ++n) \
        acc[(M0) + 1][n] = __builtin_amdgcn_mfma_f32_16x16x32_bf16(E0, BF[2 * n], acc[(M0) + 1][n], 0, 0, 0); \
    _Pragma("unroll") \
    for (int n = 0; n < 4; ++n) \
        acc[M0][n] = __builtin_amdgcn_mfma_f32_16x16x32_bf16(A1, BF[2 * n + 1], acc[M0][n], 0, 0, 0); \
    _Pragma("unroll") \
    for (int n = 0; n < 4; ++n) \
        acc[(M0) + 1][n] = __builtin_amdgcn_mfma_f32_16x16x32_bf16(E1, BF[2 * n + 1], acc[(M0) + 1][n], 0, 0, 0); \
    __builtin_amdgcn_s_setprio(0); \
} while (0)

// Rotated tile body. M6P: run prev tile's m6 at entry (operands ya + BN).
#define TILE_ROT(CUR, BF, BN, M6P, DO_STA, DO_STB, DO_RDB, DO_PFA, DO_ENDBAR) do { \
    const short* aBase = smem + (CUR) * 32768 + wm * 8192; \
    if (M6P) MFMA2(ya0, ya1, yb0, yb1, 6, BN); \
    if (DO_STA) STAGE_A(64, 1 - (CUR)); \
    if (DO_STB) STAGE_B(128, (CUR)); \
    RDA(ya0, ya1, yb0, yb1, 2, aBase); \
    MFMA2(xa0, xa1, xb0, xb1, 0, BF); \
    RDA(xa0, xa1, xb0, xb1, 4, aBase); \
    MFMA2(ya0, ya1, yb0, yb1, 2, BF); \
    if (DO_RDB) RDB(BN, 1 - (CUR)); \
    RDA(ya0, ya1, yb0, yb1, 6, aBase); \
    MFMA2(xa0, xa1, xb0, xb1, 4, BF); \
    if (DO_ENDBAR) { \
        asm volatile("s_waitcnt lgkmcnt(4)" ::: "memory"); \
        asm volatile("s_waitcnt vmcnt(0)" ::: "memory"); \
        __builtin_amdgcn_s_barrier(); \
    } \
    if (DO_PFA) RDA(xa0, xa1, xb0, xb1, 0, smem + (1 - (CUR)) * 32768 + wm * 8192); \
    gA += 64; gB += 64; \
} while (0)

    f32x4 acc[8][4];
#pragma unroll
    for (int m = 0; m < 8; ++m)
#pragma unroll
        for (int n = 0; n < 4; ++n) acc[m][n] = 0.f;

    short8 B0r[8], B1r[8];
    short8 xa0, xa1, xb0, xb1, ya0, ya1, yb0, yb1;

    // prologue: stage kt0 (A+B) + kt1.B; drain; prefetch Bf(0) + A.m0(0)
    STAGE_A(0, 0);
    STAGE_B(0, 0);
    STAGE_B(64, 1);
    asm volatile("s_waitcnt vmcnt(0)" ::: "memory");   // kt0 + kt1.B resident
    __builtin_amdgcn_s_barrier();
    RDB(B0r, 0);
    RDA(xa0, xa1, xb0, xb1, 0, smem + wm * 8192);
    asm volatile("s_waitcnt lgkmcnt(0)" ::: "memory"); // regs loaded before STB(2)
    __builtin_amdgcn_s_barrier();

    // kt = 0 (no prev m6)
    TILE_ROT(0, B0r, B1r, 0, 1, 1, 1, 1, 1);
    for (int i = 0; i < 30; ++i) {              // kt = 1..60
        TILE_ROT(1, B1r, B0r, 1, 1, 1, 1, 1, 1);
        TILE_ROT(0, B0r, B1r, 1, 1, 1, 1, 1, 1);
    }
    TILE_ROT(1, B1r, B0r, 1, 1, 1, 1, 1, 1);    // kt = 61
    TILE_ROT(0, B0r, B1r, 1, 1, 0, 1, 1, 1);    // kt = 62: no STB(64)
    TILE_ROT(1, B1r, B0r, 1, 0, 0, 0, 0, 0);    // kt = 63: compute only
    MFMA2(ya0, ya1, yb0, yb1, 6, B1r);          // m6 of kt = 63

    // epilogue: C/D layout col=lane&15, row=(lane>>4)*4+reg
    const size_t r0 = (size_t)bm * 256 + wm * 128 + (lk << 2);
    const size_t cb0 = (size_t)bn * 256 + wn * 64 + lr;
#pragma unroll
    for (int m = 0; m < 8; ++m)
#pragma unroll
        for (int n = 0; n < 4; ++n) {
            const size_t col = cb0 + n * 16;
#pragma unroll
            for (int j = 0; j < 4; ++j)
                Z[(r0 + m * 16 + j) * MDIM + col] = acc[m][n][j];
        }
}

// ---------------------------------------------------------------------------
extern "C" void kernel_launch(void* const* d_in, const int* in_sizes, int n_in,
                              void* d_out, int out_size, void* d_ws, size_t ws_size,
                              hipStream_t stream) {
    const float* input  = (const float*)d_in[0];
    const int*   Qidxs  = (const int*)d_in[1];
    const float* cbvals = (const float*)d_in[2];
    const float* SU     = (const float*)d_in[3];
    const float* SV     = (const float*)d_in[4];
    const float* Wscale = (const float*)d_in[5];
    const float* A      = (const float*)d_in[6];
    const float* B      = (const float*)d_in[7];
    float* out = (float*)d_out;

    __hip_bfloat16* xbf = (__hip_bfloat16*)d_ws;
    __hip_bfloat16* wbf = (__hip_bfloat16*)((char*)d_ws + (size_t)T_ROWS * NDIM * 2);

    fwht_in_kernel<<<T_ROWS, 256, 0, stream>>>(input, SU, xbf);
    dequant_kernel<<<dim3(MDIM / 64, MDIM / 64), 256, 0, stream>>>(
        Qidxs, cbvals, Wscale, A, B, wbf);
    gemm256_kernel<<<(T_ROWS / 256) * (MDIM / 256), 512, 0, stream>>>(xbf, wbf, out);
    fwht_out_kernel<<<T_ROWS, 256, 0, stream>>>(out, SV);
}